// Round 8
// baseline (546.088 us; speedup 1.0000x reference)
//
#include <hip/hip_runtime.h>
#include <hip/hip_cooperative_groups.h>
#include <math.h>

namespace cg = cooperative_groups;

#define CCH   256
#define NPIX  4096
#define BATCH 4

typedef __attribute__((ext_vector_type(8))) short s16x8;
typedef __attribute__((ext_vector_type(4))) short s16x4;
typedef __attribute__((ext_vector_type(4))) float f32x4;

__device__ __forceinline__ unsigned short f2bf(float f) {
    unsigned int u = __float_as_uint(f);
    u += 0x7fff + ((u >> 16) & 1);          // RNE; values are finite
    return (unsigned short)(u >> 16);
}
__device__ __forceinline__ float bf2f(unsigned short h) {
    return __uint_as_float(((unsigned int)h) << 16);
}

// q/k frag (16x16x32 A/B layout), element for (pixel n, dim d):
//   tile = n>>4, lane = (d>>3)*16 + (n&15), elem = d&7
__device__ __forceinline__ size_t qk_addr(int b, int n, int d) {
    return ((((size_t)b * 256 + (n >> 4)) * 64 + ((d >> 3) << 4) + (n & 15)) << 3) + (d & 7);
}
// v frag: standard A-layout for PV; k = j (32-step), m = c (16-tile):
__device__ __forceinline__ size_t v_addr(int b, int j, int c) {
    return ((((((size_t)b * 64 + (j >> 6)) * 16 + (c >> 4)) * 2 + ((j >> 5) & 1)) * 64
            + (((j >> 3) & 3) << 4) + (c & 15)) << 3) + (j & 7);
}

// ======================= shared unit functions =======================

// one (rt, kb) W-cast unit (verbatim logic from the verified wcast_kernel)
__device__ __forceinline__ void wcast_unit(
    const int rt, const int kb, const int lane, const bool do_bias,
    const float* __restrict__ Wq, const float* __restrict__ bq,
    const float* __restrict__ Wk, const float* __restrict__ bk,
    const float* __restrict__ Wv, const float* __restrict__ bv,
    unsigned short* __restrict__ wfh, unsigned short* __restrict__ wfl,
    float* __restrict__ bias_ws)
{
    const int l15 = lane & 15, quad = lane >> 4;
    const float *Ws, *bs; int roff; float scale = 1.0f;
    if (rt < 2)      { Ws = Wq; bs = bq; roff = rt * 16;      scale = 1.44269504f; }
    else if (rt < 4) { Ws = Wk; bs = bk; roff = (rt - 2) * 16; }
    else             { Ws = Wv; bs = bv; roff = (rt - 4) * 16; }

    const float* wrow = Ws + (size_t)(roff + l15) * CCH + quad * 8;
    s16x8 h, l;
    #pragma unroll
    for (int d = 0; d < 8; ++d) {
        float wv = wrow[kb * 32 + d] * scale;
        unsigned short hh = f2bf(wv);
        h[d] = (short)hh;
        l[d] = (short)f2bf(wv - bf2f(hh));
    }
    *(s16x8*)&wfh[(((size_t)rt * 8 + kb) * 64 + lane) * 8] = h;
    if (rt < 4) *(s16x8*)&wfl[(((size_t)rt * 8 + kb) * 64 + lane) * 8] = l;
    if (do_bias && lane < 16) bias_ws[rt * 16 + lane] = bs[roff + lane] * scale;
}

// one (pb, nt, rh) projection unit (verbatim logic from the R6-verified proj)
__device__ __forceinline__ void proj_unit(
    const int pb, const int nt, const int rh, const int lane,
    const float* __restrict__ x,
    const unsigned short* __restrict__ wfh, const unsigned short* __restrict__ wfl,
    const float* __restrict__ bias_ws,
    unsigned short* __restrict__ q_hi, unsigned short* __restrict__ q_lo,
    unsigned short* __restrict__ k_hi, unsigned short* __restrict__ k_lo,
    unsigned short* __restrict__ v_frag)
{
    const int l15 = lane & 15, quad = lane >> 4;
    const float* xb = x + (size_t)pb * CCH * NPIX + nt * 16 + l15;

    f32x4 aq0 = {0.f, 0.f, 0.f, 0.f};
    f32x4 aq1 = {0.f, 0.f, 0.f, 0.f};
    f32x4 av[4];
    #pragma unroll
    for (int i = 0; i < 4; ++i) av[i] = (f32x4){0.f, 0.f, 0.f, 0.f};

    #pragma unroll 2
    for (int kb = 0; kb < 8; ++kb) {
        s16x8 xh, xl;
        #pragma unroll
        for (int d = 0; d < 8; ++d) {
            float xv = xb[(size_t)(kb * 32 + quad * 8 + d) * NPIX];
            unsigned short h = f2bf(xv);
            xh[d] = (short)h;
            xl[d] = (short)f2bf(xv - bf2f(h));
        }
        {
            const s16x8 ah = *(const s16x8*)&wfh[(((size_t)rh * 8 + kb) * 64 + lane) * 8];
            const s16x8 al = *(const s16x8*)&wfl[(((size_t)rh * 8 + kb) * 64 + lane) * 8];
            aq0 = __builtin_amdgcn_mfma_f32_16x16x32_bf16(ah, xh, aq0, 0, 0, 0);
            aq1 = __builtin_amdgcn_mfma_f32_16x16x32_bf16(ah, xl, aq1, 0, 0, 0);
            aq1 = __builtin_amdgcn_mfma_f32_16x16x32_bf16(al, xh, aq1, 0, 0, 0);
        }
        #pragma unroll
        for (int i = 0; i < 4; ++i) {
            const int rt = 4 + rh * 4 + i;
            const s16x8 ah = *(const s16x8*)&wfh[(((size_t)rt * 8 + kb) * 64 + lane) * 8];
            av[i] = __builtin_amdgcn_mfma_f32_16x16x32_bf16(ah, xh, av[i], 0, 0, 0);
        }
    }

    const int n = nt * 16 + l15;
    {
        s16x4 h4, l4;
        #pragma unroll
        for (int rr = 0; rr < 4; ++rr) {
            const int rloc = quad * 4 + rr;
            const float val = aq0[rr] + aq1[rr] + bias_ws[rh * 16 + rloc];
            const unsigned short h = f2bf(val);
            h4[rr] = (short)h;
            l4[rr] = (short)f2bf(val - bf2f(h));
        }
        if (rh < 2) {
            const size_t a = qk_addr(pb, n, rh * 16 + quad * 4);
            *(s16x4*)&q_hi[a] = h4;
            *(s16x4*)&q_lo[a] = l4;
        } else {
            const size_t a = qk_addr(pb, n, (rh - 2) * 16 + quad * 4);
            *(s16x4*)&k_hi[a] = h4;
            *(s16x4*)&k_lo[a] = l4;
        }
    }
    #pragma unroll
    for (int i = 0; i < 4; ++i) {
        const int vt = rh * 4 + i;
        #pragma unroll
        for (int rr = 0; rr < 4; ++rr) {
            const int rloc = quad * 4 + rr;
            const float val = av[i][rr] + bias_ws[(4 + vt) * 16 + rloc];
            v_frag[v_addr(pb, n, vt * 16 + rloc)] = f2bf(val);
        }
    }
}

// ======================= attn (R2 merged 1024-thread structure, HW-verified) =======================
union AttnShMem {
    unsigned short p[2][2][2][4][512];   // [ih][jh][buf][frag][lane*8] = 32 KB
    f32x4 comb[2][2][4][2][64];          // [ih][jh_src][ch][ct-slot][lane] = 32 KB (epilogue only)
};

#define BARRIER_LGKM() do { \
    asm volatile("s_waitcnt lgkmcnt(0)" ::: "memory"); \
    __builtin_amdgcn_s_barrier(); \
    asm volatile("" ::: "memory"); \
} while (0)

#define QK_STEP(KFH, KFL, BUFC) do { \
    f32x4 a0 = __builtin_amdgcn_mfma_f32_16x16x32_bf16((KFH), qfl0, (f32x4){0.f,0.f,0.f,0.f}, 0, 0, 0); \
    a0 = __builtin_amdgcn_mfma_f32_16x16x32_bf16((KFL), qfh0, a0, 0, 0, 0); \
    a0 = __builtin_amdgcn_mfma_f32_16x16x32_bf16((KFH), qfh0, a0, 0, 0, 0); \
    f32x4 a1 = __builtin_amdgcn_mfma_f32_16x16x32_bf16((KFH), qfl1, (f32x4){0.f,0.f,0.f,0.f}, 0, 0, 0); \
    a1 = __builtin_amdgcn_mfma_f32_16x16x32_bf16((KFL), qfh1, a1, 0, 0, 0); \
    a1 = __builtin_amdgcn_mfma_f32_16x16x32_bf16((KFH), qfh1, a1, 0, 0, 0); \
    unsigned int u0 = __float_as_uint(__builtin_exp2f(a0[0])) + 0x8000u; \
    unsigned int u1 = __float_as_uint(__builtin_exp2f(a0[1])) + 0x8000u; \
    unsigned int u2 = __float_as_uint(__builtin_exp2f(a0[2])) + 0x8000u; \
    unsigned int u3 = __float_as_uint(__builtin_exp2f(a0[3])) + 0x8000u; \
    uint2 pv; \
    pv.x = __builtin_amdgcn_perm(u1, u0, 0x07060302u); \
    pv.y = __builtin_amdgcn_perm(u3, u2, 0x07060302u); \
    *(uint2*)&shm.p[ih][jh][BUFC][0 * 2 + pfrag_jj][(prow * 16 + l15) * 8 + pcol] = pv; \
    u0 = __float_as_uint(__builtin_exp2f(a1[0])) + 0x8000u; \
    u1 = __float_as_uint(__builtin_exp2f(a1[1])) + 0x8000u; \
    u2 = __float_as_uint(__builtin_exp2f(a1[2])) + 0x8000u; \
    u3 = __float_as_uint(__builtin_exp2f(a1[3])) + 0x8000u; \
    uint2 pw; \
    pw.x = __builtin_amdgcn_perm(u1, u0, 0x07060302u); \
    pw.y = __builtin_amdgcn_perm(u3, u2, 0x07060302u); \
    *(uint2*)&shm.p[ih][jh][BUFC][1 * 2 + pfrag_jj][(prow * 16 + l15) * 8 + pcol] = pw; \
} while (0)

#define ATTN_BODY(T, BUFC, KU_H, KU_L, KL_H, KL_L, DO_QK) do { \
    const int jt = jh * 32 + (T); \
    const s16x8 pf0 = *(const s16x8*)&shm.p[ih][jh][BUFC][0][lane * 8]; \
    const s16x8 pf1 = *(const s16x8*)&shm.p[ih][jh][BUFC][1][lane * 8]; \
    const s16x8 pf2 = *(const s16x8*)&shm.p[ih][jh][BUFC][2][lane * 8]; \
    const s16x8 pf3 = *(const s16x8*)&shm.p[ih][jh][BUFC][3][lane * 8]; \
    const size_t vbase = (((size_t)jt * 16 + ch * 4) * 2) * 512; \
    const s16x8 v0 = *(const s16x8*)(vb + vbase); \
    const s16x8 v1 = *(const s16x8*)(vb + vbase + 512); \
    const s16x8 v2 = *(const s16x8*)(vb + vbase + 1024); \
    const s16x8 v3 = *(const s16x8*)(vb + vbase + 1536); \
    if (DO_QK) { QK_STEP(KU_H, KU_L, (BUFC) ^ 1); } \
    { \
        const int tpp = ((T) + 2 < 32) ? (T) + 2 : 0; \
        const size_t koff = (size_t)((jh * 32 + tpp) * 4 + ch) * 512; \
        KL_H = *(const s16x8*)(khb + koff); \
        KL_L = *(const s16x8*)(klb + koff); \
    } \
    if (ch == 0) { \
        lacc = __builtin_amdgcn_mfma_f32_16x16x32_bf16(ones, pf0, lacc, 0, 0, 0); \
        lacc = __builtin_amdgcn_mfma_f32_16x16x32_bf16(ones, pf1, lacc, 0, 0, 0); \
    } else if (ch == 1) { \
        lacc = __builtin_amdgcn_mfma_f32_16x16x32_bf16(ones, pf2, lacc, 0, 0, 0); \
        lacc = __builtin_amdgcn_mfma_f32_16x16x32_bf16(ones, pf3, lacc, 0, 0, 0); \
    } \
    BARRIER_LGKM(); \
    const s16x8 v4 = *(const s16x8*)(vb + vbase + 2048); \
    const s16x8 v5 = *(const s16x8*)(vb + vbase + 2560); \
    const s16x8 v6 = *(const s16x8*)(vb + vbase + 3072); \
    const s16x8 v7 = *(const s16x8*)(vb + vbase + 3584); \
    __builtin_amdgcn_s_setprio(1); \
    acc[0] = __builtin_amdgcn_mfma_f32_16x16x32_bf16(v0, pf0, acc[0], 0, 0, 0); \
    acc[0] = __builtin_amdgcn_mfma_f32_16x16x32_bf16(v1, pf1, acc[0], 0, 0, 0); \
    acc[1] = __builtin_amdgcn_mfma_f32_16x16x32_bf16(v0, pf2, acc[1], 0, 0, 0); \
    acc[1] = __builtin_amdgcn_mfma_f32_16x16x32_bf16(v1, pf3, acc[1], 0, 0, 0); \
    acc[2] = __builtin_amdgcn_mfma_f32_16x16x32_bf16(v2, pf0, acc[2], 0, 0, 0); \
    acc[2] = __builtin_amdgcn_mfma_f32_16x16x32_bf16(v3, pf1, acc[2], 0, 0, 0); \
    acc[3] = __builtin_amdgcn_mfma_f32_16x16x32_bf16(v2, pf2, acc[3], 0, 0, 0); \
    acc[3] = __builtin_amdgcn_mfma_f32_16x16x32_bf16(v3, pf3, acc[3], 0, 0, 0); \
    acc[4] = __builtin_amdgcn_mfma_f32_16x16x32_bf16(v4, pf0, acc[4], 0, 0, 0); \
    acc[4] = __builtin_amdgcn_mfma_f32_16x16x32_bf16(v5, pf1, acc[4], 0, 0, 0); \
    acc[5] = __builtin_amdgcn_mfma_f32_16x16x32_bf16(v4, pf2, acc[5], 0, 0, 0); \
    acc[5] = __builtin_amdgcn_mfma_f32_16x16x32_bf16(v5, pf3, acc[5], 0, 0, 0); \
    acc[6] = __builtin_amdgcn_mfma_f32_16x16x32_bf16(v6, pf0, acc[6], 0, 0, 0); \
    acc[6] = __builtin_amdgcn_mfma_f32_16x16x32_bf16(v7, pf1, acc[6], 0, 0, 0); \
    acc[7] = __builtin_amdgcn_mfma_f32_16x16x32_bf16(v6, pf2, acc[7], 0, 0, 0); \
    acc[7] = __builtin_amdgcn_mfma_f32_16x16x32_bf16(v7, pf3, acc[7], 0, 0, 0); \
    __builtin_amdgcn_s_setprio(0); \
} while (0)

__device__ __forceinline__ void attn_impl(
    const int f, const int t, AttnShMem& shm, float (&lds_l)[2][2][2][16],
    const unsigned short* __restrict__ q_hi, const unsigned short* __restrict__ q_lo,
    const unsigned short* __restrict__ k_hi, const unsigned short* __restrict__ k_lo,
    const unsigned short* __restrict__ v_frag,
    const float* __restrict__ x, float* __restrict__ out)
{
    const int w = t >> 6, lane = t & 63, l15 = lane & 15, quad = lane >> 4;
    const int ih = w >> 3, jh = (w >> 2) & 1, ch = w & 3;

    const int xcd = f & 7;
    const int b = xcd >> 1;
    const int ib = ((xcd & 1) << 5) + (f >> 3);   // i-block 0..63 (64 pixels)

    s16x8 qfh0, qfl0, qfh1, qfl1;
    {
        const int ti0 = ib * 4 + ih * 2;
        const size_t qo0 = ((size_t)b * 256 + ti0 + 0) * 512 + (size_t)lane * 8;
        const size_t qo1 = ((size_t)b * 256 + ti0 + 1) * 512 + (size_t)lane * 8;
        qfh0 = *(const s16x8*)(q_hi + qo0);  qfl0 = *(const s16x8*)(q_lo + qo0);
        qfh1 = *(const s16x8*)(q_hi + qo1);  qfl1 = *(const s16x8*)(q_lo + qo1);
    }

    const s16x8 ones = { (short)0x3F80, (short)0x3F80, (short)0x3F80, (short)0x3F80,
                         (short)0x3F80, (short)0x3F80, (short)0x3F80, (short)0x3F80 };

    f32x4 acc[8];
    #pragma unroll
    for (int i = 0; i < 8; ++i) acc[i] = (f32x4){0.f, 0.f, 0.f, 0.f};
    f32x4 lacc = {0.f, 0.f, 0.f, 0.f};

    const unsigned short* khb = k_hi + (size_t)b * 131072 + (size_t)lane * 8;
    const unsigned short* klb = k_lo + (size_t)b * 131072 + (size_t)lane * 8;
    const unsigned short* vb  = v_frag + (size_t)b * 1048576 + (size_t)lane * 8;

    const int prow = ((ch & 1) << 1) + (quad >> 1);
    const int pcol = ((quad & 1) << 2);
    const int pfrag_jj = ch >> 1;

    s16x8 ka_h, ka_l, kb_h, kb_l;
    {
        const size_t k0 = (size_t)((jh * 32 + 0) * 4 + ch) * 512;
        ka_h = *(const s16x8*)(khb + k0);
        ka_l = *(const s16x8*)(klb + k0);
    }
    QK_STEP(ka_h, ka_l, 0);
    {
        const size_t k1 = (size_t)((jh * 32 + 1) * 4 + ch) * 512;
        ka_h = *(const s16x8*)(khb + k1);
        ka_l = *(const s16x8*)(klb + k1);
    }
    BARRIER_LGKM();

    #pragma unroll 1
    for (int t2 = 0; t2 < 16; ++t2) {
        ATTN_BODY(2 * t2,     0, ka_h, ka_l, kb_h, kb_l, 1);
        ATTN_BODY(2 * t2 + 1, 1, kb_h, kb_l, ka_h, ka_l, (t2 < 15));
    }

    // epilogue: 2-pass comb exchange overlaid on p (dead after loop; R2-verified)
    if (ch < 2 && lane < 16) lds_l[ih][jh][ch][lane] = lacc[0];
    if (jh == 0) { shm.comb[ih][0][ch][0][lane] = acc[1]; shm.comb[ih][0][ch][1][lane] = acc[3]; }
    else         { shm.comb[ih][1][ch][0][lane] = acc[0]; shm.comb[ih][1][ch][1][lane] = acc[2]; }
    __syncthreads();
    const float linv = 1.f / (lds_l[ih][0][jh][l15] + lds_l[ih][1][jh][l15]);
    const int ibase = (ib * 4 + ih * 2 + jh) * 16 + l15;
    {
        f32x4 a0 = (jh == 0) ? acc[0] : acc[1];
        f32x4 a1 = (jh == 0) ? acc[2] : acc[3];
        a0 += shm.comb[ih][1 - jh][ch][0][lane];
        a1 += shm.comb[ih][1 - jh][ch][1][lane];
        #pragma unroll
        for (int rr = 0; rr < 4; ++rr) {
            const int c0 = ch * 64 + 0 * 16 + quad * 4 + rr;
            const int c1 = ch * 64 + 1 * 16 + quad * 4 + rr;
            const size_t i0 = ((size_t)b * CCH + c0) * NPIX + ibase;
            const size_t i1 = ((size_t)b * CCH + c1) * NPIX + ibase;
            out[i0] = a0[rr] * linv + x[i0];
            out[i1] = a1[rr] * linv + x[i1];
        }
    }
    __syncthreads();
    if (jh == 0) { shm.comb[ih][0][ch][0][lane] = acc[5]; shm.comb[ih][0][ch][1][lane] = acc[7]; }
    else         { shm.comb[ih][1][ch][0][lane] = acc[4]; shm.comb[ih][1][ch][1][lane] = acc[6]; }
    __syncthreads();
    {
        f32x4 a2 = (jh == 0) ? acc[4] : acc[5];
        f32x4 a3 = (jh == 0) ? acc[6] : acc[7];
        a2 += shm.comb[ih][1 - jh][ch][0][lane];
        a3 += shm.comb[ih][1 - jh][ch][1][lane];
        #pragma unroll
        for (int rr = 0; rr < 4; ++rr) {
            const int c2 = ch * 64 + 2 * 16 + quad * 4 + rr;
            const int c3 = ch * 64 + 3 * 16 + quad * 4 + rr;
            const size_t i2 = ((size_t)b * CCH + c2) * NPIX + ibase;
            const size_t i3 = ((size_t)b * CCH + c3) * NPIX + ibase;
            out[i2] = a2[rr] * linv + x[i2];
            out[i3] = a3[rr] * linv + x[i3];
        }
    }
}

// ======================= standalone kernels (fallback path, R6-verified logic) =======================
__global__ __launch_bounds__(64) void wcast_kernel(
    const float* __restrict__ Wq, const float* __restrict__ bq,
    const float* __restrict__ Wk, const float* __restrict__ bk,
    const float* __restrict__ Wv, const float* __restrict__ bv,
    unsigned short* __restrict__ wfh, unsigned short* __restrict__ wfl,
    float* __restrict__ bias_ws)
{
    const int rt = blockIdx.x, lane = threadIdx.x;
    for (int kb = 0; kb < 8; ++kb)
        wcast_unit(rt, kb, lane, kb == 0, Wq, bq, Wk, bk, Wv, bv, wfh, wfl, bias_ws);
}

__global__ __launch_bounds__(256, 4) void proj_kernel(
    const float* __restrict__ x,
    const unsigned short* __restrict__ wfh, const unsigned short* __restrict__ wfl,
    const float* __restrict__ bias_ws,
    unsigned short* __restrict__ q_hi, unsigned short* __restrict__ q_lo,
    unsigned short* __restrict__ k_hi, unsigned short* __restrict__ k_lo,
    unsigned short* __restrict__ v_frag)
{
    proj_unit(blockIdx.y, blockIdx.x, threadIdx.x >> 6, threadIdx.x & 63,
              x, wfh, wfl, bias_ws, q_hi, q_lo, k_hi, k_lo, v_frag);
}

__global__ __launch_bounds__(1024, 4) void attn_kernel(
    const unsigned short* __restrict__ q_hi, const unsigned short* __restrict__ q_lo,
    const unsigned short* __restrict__ k_hi, const unsigned short* __restrict__ k_lo,
    const unsigned short* __restrict__ v_frag,
    const float* __restrict__ x, float* __restrict__ out)
{
    __shared__ AttnShMem shm;
    __shared__ float lds_l[2][2][2][16];
    attn_impl(blockIdx.x, threadIdx.x, shm, lds_l, q_hi, q_lo, k_hi, k_lo, v_frag, x, out);
}

// ======================= fused cooperative kernel =======================
// 256 blocks x 1024 threads: needs only 1 block/CU co-residency (LDS 33.3KB,
// VGPR <= 128 via launch_bounds) -- large validation margin vs the failed
// exact-fit 512-block attempt.  Phases: wcast (160 waves) -> proj (1024
// wave-units) -> attn (R2 merged structure), grid.sync + threadfence between.
__global__ __launch_bounds__(1024, 4) void fused_kernel(
    const float* __restrict__ x,
    const float* __restrict__ Wq, const float* __restrict__ bq,
    const float* __restrict__ Wk, const float* __restrict__ bk,
    const float* __restrict__ Wv, const float* __restrict__ bv,
    unsigned short* __restrict__ wfh, unsigned short* __restrict__ wfl,
    float* __restrict__ bias_ws,
    unsigned short* __restrict__ q_hi, unsigned short* __restrict__ q_lo,
    unsigned short* __restrict__ k_hi, unsigned short* __restrict__ k_lo,
    unsigned short* __restrict__ v_frag,
    float* __restrict__ out)
{
    __shared__ AttnShMem shm;
    __shared__ float lds_l[2][2][2][16];

    cg::grid_group grid = cg::this_grid();

    const int t = threadIdx.x;
    const int w = t >> 6, lane = t & 63;
    const int f = blockIdx.x;                 // 0..255

    // phase 0: wcast — 160 (rt,kb) wave-units
    {
        const int gw = f * 16 + w;
        if (gw < 160)
            wcast_unit(gw >> 3, gw & 7, lane, (gw & 7) == 0,
                       Wq, bq, Wk, bk, Wv, bv, wfh, wfl, bias_ws);
    }
    __threadfence();
    grid.sync();
    __threadfence();

    // phase 1: proj — 1024 (pb,nt) units x 4 rh-waves
    {
        const int o = f * 4 + (w >> 2);       // 0..1023
        proj_unit(o >> 8, o & 255, w & 3, lane,
                  x, wfh, wfl, bias_ws, q_hi, q_lo, k_hi, k_lo, v_frag);
    }
    __threadfence();
    grid.sync();
    __threadfence();

    // phase 2: attn
    attn_impl(f, t, shm, lds_l, q_hi, q_lo, k_hi, k_lo, v_frag, x, out);
}

extern "C" void kernel_launch(void* const* d_in, const int* in_sizes, int n_in,
                              void* d_out, int out_size, void* d_ws, size_t ws_size,
                              hipStream_t stream) {
    const float* x  = (const float*)d_in[0];
    const float* Wq = (const float*)d_in[1];
    const float* bq = (const float*)d_in[2];
    const float* Wk = (const float*)d_in[3];
    const float* bk = (const float*)d_in[4];
    const float* Wv = (const float*)d_in[5];
    const float* bv = (const float*)d_in[6];
    float* out = (float*)d_out;

    unsigned short* ws = (unsigned short*)d_ws;
    unsigned short* q_hi   = ws;                 //   524,288
    unsigned short* q_lo   = ws + 524288;        //   524,288
    unsigned short* k_hi   = ws + 1048576;       //   524,288
    unsigned short* k_lo   = ws + 1572864;       //   524,288
    unsigned short* v_frag = ws + 2097152;       // 4,194,304
    unsigned short* wfh    = ws + 6291456;       //    81,920
    unsigned short* wfl    = ws + 6373376;       //    16,384
    float*          bias_ws = (float*)(ws + 6389760);  // 320 floats

    void* kargs[] = {
        (void*)&x,
        (void*)&Wq, (void*)&bq, (void*)&Wk, (void*)&bk, (void*)&Wv, (void*)&bv,
        (void*)&wfh, (void*)&wfl, (void*)&bias_ws,
        (void*)&q_hi, (void*)&q_lo, (void*)&k_hi, (void*)&k_lo, (void*)&v_frag,
        (void*)&out
    };
    hipError_t e = hipLaunchCooperativeKernel((const void*)fused_kernel,
                                              dim3(256), dim3(1024), kargs, 0, stream);
    if (e != hipSuccess) {
        (void)hipGetLastError();   // clear error state; use proven 3-kernel path
        wcast_kernel<<<20, 64, 0, stream>>>(Wq, bq, Wk, bk, Wv, bv, wfh, wfl, bias_ws);
        proj_kernel<<<dim3(256, BATCH), 256, 0, stream>>>(x, wfh, wfl, bias_ws,
                                                          q_hi, q_lo, k_hi, k_lo, v_frag);
        attn_kernel<<<256, 1024, 0, stream>>>(q_hi, q_lo, k_hi, k_lo, v_frag, x, out);
    }
}

// Round 9
// 144.991 us; speedup vs baseline: 3.7663x; 3.7663x over previous
//
#include <hip/hip_runtime.h>
#include <math.h>

#define CCH   256
#define NPIX  4096
#define BATCH 4

typedef __attribute__((ext_vector_type(8))) short    s16x8;
typedef __attribute__((ext_vector_type(4))) short    s16x4;
typedef __attribute__((ext_vector_type(8))) _Float16 f16x8;
typedef __attribute__((ext_vector_type(4))) float    f32x4;

__device__ __forceinline__ unsigned short f2bf(float f) {
    unsigned int u = __float_as_uint(f);
    u += 0x7fff + ((u >> 16) & 1);          // RNE; values are finite
    return (unsigned short)(u >> 16);
}
__device__ __forceinline__ float bf2f(unsigned short h) {
    return __uint_as_float(((unsigned int)h) << 16);
}
__device__ __forceinline__ unsigned short f2h(float f) {
    _Float16 h = (_Float16)f;               // v_cvt_f16_f32, RNE
    return *(unsigned short*)&h;
}
__device__ __forceinline__ float h2f(unsigned short u) {
    _Float16 h = *(_Float16*)&u;
    return (float)h;
}

// q/k frag (16x16x32 A/B layout), element for (pixel n, dim d):
//   tile = n>>4, lane = (d>>3)*16 + (n&15), elem = d&7
__device__ __forceinline__ size_t qk_addr(int b, int n, int d) {
    return ((((size_t)b * 256 + (n >> 4)) * 64 + ((d >> 3) << 4) + (n & 15)) << 3) + (d & 7);
}
// v frag: standard A-layout for PV; k = j (32-step), m = c (16-tile):
__device__ __forceinline__ size_t v_addr(int b, int j, int c) {
    return ((((((size_t)b * 64 + (j >> 6)) * 16 + (c >> 4)) * 2 + ((j >> 5) & 1)) * 64
            + (((j >> 3) & 3) << 4) + (c & 15)) << 3) + (j & 7);
}

// ---------------- W -> A-frag fp16 (hi/lo for q,k; hi for v), once ----------------
// All proj MFMAs are now f16-flavor; W frags hold fp16 bit patterns.
__global__ __launch_bounds__(64) void wcast_kernel(
    const float* __restrict__ Wq, const float* __restrict__ bq,
    const float* __restrict__ Wk, const float* __restrict__ bk,
    const float* __restrict__ Wv, const float* __restrict__ bv,
    unsigned short* __restrict__ wfh, unsigned short* __restrict__ wfl,
    float* __restrict__ bias_ws)
{
    const int rt = blockIdx.x;
    const int lane = threadIdx.x, l15 = lane & 15, quad = lane >> 4;
    const float *Ws, *bs; int roff; float scale = 1.0f;
    if (rt < 2)      { Ws = Wq; bs = bq; roff = rt * 16;      scale = 1.44269504f; }
    else if (rt < 4) { Ws = Wk; bs = bk; roff = (rt - 2) * 16; }
    else             { Ws = Wv; bs = bv; roff = (rt - 4) * 16; }

    const float* wrow = Ws + (size_t)(roff + l15) * CCH + quad * 8;
    for (int kb = 0; kb < 8; ++kb) {
        s16x8 h, l;
        #pragma unroll
        for (int d = 0; d < 8; ++d) {
            float wv = wrow[kb * 32 + d] * scale;
            unsigned short hh = f2h(wv);
            h[d] = (short)hh;
            l[d] = (short)f2h(wv - h2f(hh));
        }
        *(s16x8*)&wfh[(((size_t)rt * 8 + kb) * 64 + lane) * 8] = h;
        if (rt < 4) *(s16x8*)&wfl[(((size_t)rt * 8 + kb) * 64 + lane) * 8] = l;
    }
    if (lane < 16) bias_ws[rt * 16 + lane] = bs[roff + lane] * scale;
}

// ---------------- fused cast+projection (fp16 internal, spill-free) ----------------
// kb outermost (one x hi/lo frag live).  Wave rh: 1 q/k tile (3-term fp16
// hi/lo, then store SINGLE fp16 q/k -- fp16's 10 mantissa bits replace the
// old bf16 hi+lo pair) + 4 v tiles (fp16 MFMA, stored bf16 for PV).
__global__ __launch_bounds__(256, 4) void proj_kernel(
    const float* __restrict__ x,
    const unsigned short* __restrict__ wfh, const unsigned short* __restrict__ wfl,
    const float* __restrict__ bias_ws,
    unsigned short* __restrict__ q_hi, unsigned short* __restrict__ k_hi,
    unsigned short* __restrict__ v_frag)
{
    const int t = threadIdx.x;
    const int rh = t >> 6, lane = t & 63, l15 = lane & 15, quad = lane >> 4;
    const int b = blockIdx.y;
    const int nt = blockIdx.x;

    const float* xb = x + (size_t)b * CCH * NPIX + nt * 16 + l15;

    f32x4 aq0 = {0.f, 0.f, 0.f, 0.f};   // qk hi*hi
    f32x4 aq1 = {0.f, 0.f, 0.f, 0.f};   // qk hi*lo + lo*hi
    f32x4 av[4];
    #pragma unroll
    for (int i = 0; i < 4; ++i) av[i] = (f32x4){0.f, 0.f, 0.f, 0.f};

    #pragma unroll 2
    for (int kb = 0; kb < 8; ++kb) {
        f16x8 xh, xl;
        #pragma unroll
        for (int d = 0; d < 8; ++d) {
            float xv = xb[(size_t)(kb * 32 + quad * 8 + d) * NPIX];
            _Float16 hh = (_Float16)xv;
            xh[d] = hh;
            xl[d] = (_Float16)(xv - (float)hh);
        }
        {
            const f16x8 ah = *(const f16x8*)&wfh[(((size_t)rh * 8 + kb) * 64 + lane) * 8];
            const f16x8 al = *(const f16x8*)&wfl[(((size_t)rh * 8 + kb) * 64 + lane) * 8];
            aq0 = __builtin_amdgcn_mfma_f32_16x16x32_f16(ah, xh, aq0, 0, 0, 0);
            aq1 = __builtin_amdgcn_mfma_f32_16x16x32_f16(ah, xl, aq1, 0, 0, 0);
            aq1 = __builtin_amdgcn_mfma_f32_16x16x32_f16(al, xh, aq1, 0, 0, 0);
        }
        #pragma unroll
        for (int i = 0; i < 4; ++i) {
            const int rt = 4 + rh * 4 + i;
            const f16x8 ah = *(const f16x8*)&wfh[(((size_t)rt * 8 + kb) * 64 + lane) * 8];
            av[i] = __builtin_amdgcn_mfma_f32_16x16x32_f16(ah, xh, av[i], 0, 0, 0);
        }
    }

    const int n = nt * 16 + l15;
    // ---- q/k store: single fp16, ushort4-vectorized ----
    {
        s16x4 h4;
        #pragma unroll
        for (int rr = 0; rr < 4; ++rr) {
            const int rloc = quad * 4 + rr;
            const float val = aq0[rr] + aq1[rr] + bias_ws[rh * 16 + rloc];
            h4[rr] = (short)f2h(val);
        }
        if (rh < 2) {
            const size_t a = qk_addr(b, n, rh * 16 + quad * 4);
            *(s16x4*)&q_hi[a] = h4;
        } else {
            const size_t a = qk_addr(b, n, (rh - 2) * 16 + quad * 4);
            *(s16x4*)&k_hi[a] = h4;
        }
    }
    // ---- v store: bf16 (PV path requires bf16 -- P overflows fp16 range) ----
    #pragma unroll
    for (int i = 0; i < 4; ++i) {
        const int vt = rh * 4 + i;
        #pragma unroll
        for (int rr = 0; rr < 4; ++rr) {
            const int rloc = quad * 4 + rr;
            const float val = av[i][rr] + bias_ws[(4 + vt) * 16 + rloc];
            v_frag[v_addr(b, n, vt * 16 + rloc)] = f2bf(val);
        }
    }
}

// ---------------- flash attention: R1-proven pipeline, fp16 QK ----------------
// 512 blocks (2/CU) x 8 waves = (jh 0..1, ch 0..3).
// CHANGE vs the 62.4us version: q,k are single fp16 frags -> QK is 2 MFMAs
// (mfma_f32_16x16x32_f16) instead of the 6-MFMA bf16 hi/lo 3-term product.
// P stays bf16 (P = 2^s reaches 2^45 -- overflows fp16); PV/lacc unchanged.
#define BARRIER_LGKM() do { \
    asm volatile("s_waitcnt lgkmcnt(0)" ::: "memory"); \
    __builtin_amdgcn_s_barrier(); \
    asm volatile("" ::: "memory"); \
} while (0)

#define QK_STEP(KF, BUFC) do { \
    f32x4 a0 = __builtin_amdgcn_mfma_f32_16x16x32_f16((KF), qf0, (f32x4){0.f,0.f,0.f,0.f}, 0, 0, 0); \
    f32x4 a1 = __builtin_amdgcn_mfma_f32_16x16x32_f16((KF), qf1, (f32x4){0.f,0.f,0.f,0.f}, 0, 0, 0); \
    unsigned int u0 = __float_as_uint(__builtin_exp2f(a0[0])) + 0x8000u; \
    unsigned int u1 = __float_as_uint(__builtin_exp2f(a0[1])) + 0x8000u; \
    unsigned int u2 = __float_as_uint(__builtin_exp2f(a0[2])) + 0x8000u; \
    unsigned int u3 = __float_as_uint(__builtin_exp2f(a0[3])) + 0x8000u; \
    uint2 pv; \
    pv.x = __builtin_amdgcn_perm(u1, u0, 0x07060302u); \
    pv.y = __builtin_amdgcn_perm(u3, u2, 0x07060302u); \
    *(uint2*)&p_lds[jh][BUFC][0 * 2 + pfrag_jj][(prow * 16 + l15) * 8 + pcol] = pv; \
    u0 = __float_as_uint(__builtin_exp2f(a1[0])) + 0x8000u; \
    u1 = __float_as_uint(__builtin_exp2f(a1[1])) + 0x8000u; \
    u2 = __float_as_uint(__builtin_exp2f(a1[2])) + 0x8000u; \
    u3 = __float_as_uint(__builtin_exp2f(a1[3])) + 0x8000u; \
    uint2 pw; \
    pw.x = __builtin_amdgcn_perm(u1, u0, 0x07060302u); \
    pw.y = __builtin_amdgcn_perm(u3, u2, 0x07060302u); \
    *(uint2*)&p_lds[jh][BUFC][1 * 2 + pfrag_jj][(prow * 16 + l15) * 8 + pcol] = pw; \
} while (0)

// One pipelined iteration.  T: current j-step; BUFC: its p_lds buffer (T&1).
// KU: K frag for tile T+1 (consumed by QK).  KL: reg prefetching tile T+2.
#define ATTN_BODY(T, BUFC, KU, KL, DO_QK) do { \
    const int jt = jh * 32 + (T); \
    /* P(T) frag reads -- latency hidden under QK(T+1) */ \
    const s16x8 pf0 = *(const s16x8*)&p_lds[jh][BUFC][0][lane * 8]; \
    const s16x8 pf1 = *(const s16x8*)&p_lds[jh][BUFC][1][lane * 8]; \
    const s16x8 pf2 = *(const s16x8*)&p_lds[jh][BUFC][2][lane * 8]; \
    const s16x8 pf3 = *(const s16x8*)&p_lds[jh][BUFC][3][lane * 8]; \
    /* V(T) first half: in flight across the barrier */ \
    const size_t vbase = (((size_t)jt * 16 + ch * 4) * 2) * 512; \
    const s16x8 v0 = *(const s16x8*)(vb + vbase); \
    const s16x8 v1 = *(const s16x8*)(vb + vbase + 512); \
    const s16x8 v2 = *(const s16x8*)(vb + vbase + 1024); \
    const s16x8 v3 = *(const s16x8*)(vb + vbase + 1536); \
    if (DO_QK) { QK_STEP(KU, (BUFC) ^ 1); } \
    /* K(T+2) prefetch (clamped dummy at tail; value unused) */ \
    { \
        const int tpp = ((T) + 2 < 32) ? (T) + 2 : 0; \
        const size_t koff = (size_t)((jh * 32 + tpp) * 4 + ch) * 512; \
        KL = *(const f16x8*)(khb + koff); \
    } \
    /* denominator partials: ch0 -> it0 (pf0,pf1), ch1 -> it1 (pf2,pf3) */ \
    if (ch == 0) { \
        lacc = __builtin_amdgcn_mfma_f32_16x16x32_bf16(ones, pf0, lacc, 0, 0, 0); \
        lacc = __builtin_amdgcn_mfma_f32_16x16x32_bf16(ones, pf1, lacc, 0, 0, 0); \
    } else if (ch == 1) { \
        lacc = __builtin_amdgcn_mfma_f32_16x16x32_bf16(ones, pf2, lacc, 0, 0, 0); \
        lacc = __builtin_amdgcn_mfma_f32_16x16x32_bf16(ones, pf3, lacc, 0, 0, 0); \
    } \
    BARRIER_LGKM(); \
    /* V(T) second half (post-barrier; first use 8 MFMAs later) */ \
    const s16x8 v4 = *(const s16x8*)(vb + vbase + 2048); \
    const s16x8 v5 = *(const s16x8*)(vb + vbase + 2560); \
    const s16x8 v6 = *(const s16x8*)(vb + vbase + 3072); \
    const s16x8 v7 = *(const s16x8*)(vb + vbase + 3584); \
    __builtin_amdgcn_s_setprio(1); \
    acc[0] = __builtin_amdgcn_mfma_f32_16x16x32_bf16(v0, pf0, acc[0], 0, 0, 0); \
    acc[0] = __builtin_amdgcn_mfma_f32_16x16x32_bf16(v1, pf1, acc[0], 0, 0, 0); \
    acc[1] = __builtin_amdgcn_mfma_f32_16x16x32_bf16(v0, pf2, acc[1], 0, 0, 0); \
    acc[1] = __builtin_amdgcn_mfma_f32_16x16x32_bf16(v1, pf3, acc[1], 0, 0, 0); \
    acc[2] = __builtin_amdgcn_mfma_f32_16x16x32_bf16(v2, pf0, acc[2], 0, 0, 0); \
    acc[2] = __builtin_amdgcn_mfma_f32_16x16x32_bf16(v3, pf1, acc[2], 0, 0, 0); \
    acc[3] = __builtin_amdgcn_mfma_f32_16x16x32_bf16(v2, pf2, acc[3], 0, 0, 0); \
    acc[3] = __builtin_amdgcn_mfma_f32_16x16x32_bf16(v3, pf3, acc[3], 0, 0, 0); \
    acc[4] = __builtin_amdgcn_mfma_f32_16x16x32_bf16(v4, pf0, acc[4], 0, 0, 0); \
    acc[4] = __builtin_amdgcn_mfma_f32_16x16x32_bf16(v5, pf1, acc[4], 0, 0, 0); \
    acc[5] = __builtin_amdgcn_mfma_f32_16x16x32_bf16(v4, pf2, acc[5], 0, 0, 0); \
    acc[5] = __builtin_amdgcn_mfma_f32_16x16x32_bf16(v5, pf3, acc[5], 0, 0, 0); \
    acc[6] = __builtin_amdgcn_mfma_f32_16x16x32_bf16(v6, pf0, acc[6], 0, 0, 0); \
    acc[6] = __builtin_amdgcn_mfma_f32_16x16x32_bf16(v7, pf1, acc[6], 0, 0, 0); \
    acc[7] = __builtin_amdgcn_mfma_f32_16x16x32_bf16(v6, pf2, acc[7], 0, 0, 0); \
    acc[7] = __builtin_amdgcn_mfma_f32_16x16x32_bf16(v7, pf3, acc[7], 0, 0, 0); \
    __builtin_amdgcn_s_setprio(0); \
} while (0)

__global__ __launch_bounds__(512, 4) void attn_kernel(
    const unsigned short* __restrict__ q_hi,
    const unsigned short* __restrict__ k_hi,
    const unsigned short* __restrict__ v_frag,
    const float* __restrict__ x, float* __restrict__ out)
{
    __shared__ unsigned short p_lds[2][2][4][512];   // [jh][dbuf][frag][lane*8] = 16 KB
    __shared__ f32x4 comb[2][4][4][64];              // [jh_src][ch][ct][lane] = 32 KB
    __shared__ float lds_l[2][2][16];

    const int t = threadIdx.x;
    const int w = t >> 6, lane = t & 63, l15 = lane & 15, quad = lane >> 4;
    const int jh = w >> 2, ch = w & 3;

    const int f = blockIdx.x;                 // 0..511; XCD-pair per batch
    const int xcd = f & 7;
    const int b = xcd >> 1;
    const int ib = ((xcd & 1) << 6) + (f >> 3);   // i-block 0..127 (32 pixels)

    f16x8 qf0, qf1;
    {
        const size_t qo0 = ((size_t)b * 256 + ib * 2 + 0) * 512 + (size_t)lane * 8;
        const size_t qo1 = ((size_t)b * 256 + ib * 2 + 1) * 512 + (size_t)lane * 8;
        qf0 = *(const f16x8*)(q_hi + qo0);
        qf1 = *(const f16x8*)(q_hi + qo1);
    }

    const s16x8 ones = { (short)0x3F80, (short)0x3F80, (short)0x3F80, (short)0x3F80,
                         (short)0x3F80, (short)0x3F80, (short)0x3F80, (short)0x3F80 };

    f32x4 acc[8];                             // [ct*2+it], constant indices only
    #pragma unroll
    for (int i = 0; i < 8; ++i) acc[i] = (f32x4){0.f, 0.f, 0.f, 0.f};
    f32x4 lacc = {0.f, 0.f, 0.f, 0.f};

    const unsigned short* khb = k_hi + (size_t)b * 131072 + (size_t)lane * 8;
    const unsigned short* vb  = v_frag + (size_t)b * 1048576 + (size_t)lane * 8;

    const int prow = ((ch & 1) << 1) + (quad >> 1);
    const int pcol = ((quad & 1) << 2);
    const int pfrag_jj = ch >> 1;

    // ---- prologue: K(0) -> QK(0) -> P(0) in buf0; prefetch K(1) ----
    f16x8 ka, kb;
    {
        const size_t k0 = (size_t)((jh * 32 + 0) * 4 + ch) * 512;
        ka = *(const f16x8*)(khb + k0);
    }
    QK_STEP(ka, 0);
    {
        const size_t k1 = (size_t)((jh * 32 + 1) * 4 + ch) * 512;
        ka = *(const f16x8*)(khb + k1);
    }
    BARRIER_LGKM();

    #pragma unroll 1
    for (int t2 = 0; t2 < 16; ++t2) {
        ATTN_BODY(2 * t2,     0, ka, kb, 1);
        ATTN_BODY(2 * t2 + 1, 1, kb, ka, (t2 < 15));
    }

    // ---- epilogue (constant indices inside wave-uniform branches) ----
    if (ch < 2 && lane < 16) lds_l[jh][ch][lane] = lacc[0];
    if (jh == 0) {          // own it0; publish it1
        #pragma unroll
        for (int ct = 0; ct < 4; ++ct)
            comb[0][ch][ct][lane] = acc[ct * 2 + 1];
    } else {                // own it1; publish it0
        #pragma unroll
        for (int ct = 0; ct < 4; ++ct)
            comb[1][ch][ct][lane] = acc[ct * 2 + 0];
    }
    __syncthreads();
    const float linv = 1.f / (lds_l[0][jh][l15] + lds_l[1][jh][l15]);
    const int ibase = (ib * 2 + jh) * 16 + l15;
    #pragma unroll
    for (int ct = 0; ct < 4; ++ct) {
        f32x4 a;
        if (jh == 0) a = acc[ct * 2 + 0];
        else         a = acc[ct * 2 + 1];
        a += comb[1 - jh][ch][ct][lane];
        #pragma unroll
        for (int rr = 0; rr < 4; ++rr) {
            const int c = ch * 64 + ct * 16 + quad * 4 + rr;
            const size_t idx = ((size_t)b * CCH + c) * NPIX + ibase;
            out[idx] = a[rr] * linv + x[idx];
        }
    }
}

extern "C" void kernel_launch(void* const* d_in, const int* in_sizes, int n_in,
                              void* d_out, int out_size, void* d_ws, size_t ws_size,
                              hipStream_t stream) {
    const float* x  = (const float*)d_in[0];
    const float* Wq = (const float*)d_in[1];
    const float* bq = (const float*)d_in[2];
    const float* Wk = (const float*)d_in[3];
    const float* bk = (const float*)d_in[4];
    const float* Wv = (const float*)d_in[5];
    const float* bv = (const float*)d_in[6];
    float* out = (float*)d_out;

    unsigned short* ws = (unsigned short*)d_ws;
    unsigned short* q_hi   = ws;                 //   524,288 (fp16)
    unsigned short* k_hi   = ws + 1048576;       //   524,288 (fp16)
    unsigned short* v_frag = ws + 2097152;       // 4,194,304 (bf16)
    unsigned short* wfh    = ws + 6291456;       //    81,920 (fp16)
    unsigned short* wfl    = ws + 6373376;       //    16,384 (fp16)
    float*          bias_ws = (float*)(ws + 6389760);  // 320 floats

    wcast_kernel<<<20, 64, 0, stream>>>(Wq, bq, Wk, bk, Wv, bv, wfh, wfl, bias_ws);
    proj_kernel<<<dim3(256, BATCH), 256, 0, stream>>>(x, wfh, wfl, bias_ws,
                                                      q_hi, k_hi, v_frag);
    attn_kernel<<<512, 512, 0, stream>>>(q_hi, k_hi, v_frag, x, out);
}